// Round 5
// baseline (599.361 us; speedup 1.0000x reference)
//
#include <hip/hip_runtime.h>
#include <math.h>

// Problem constants (from setup_inputs): B=8, J=4, N=4, M=16, K=3, D=32768
constexpr int B_ = 8;
constexpr int J_ = 4;
constexpr int N_ = 4;
constexpr int M_ = 16;
constexpr int K_ = 3;
constexpr int D_ = 32768;
constexpr float EPS_ = 1e-8f;
constexpr float TEMP_INV = 2.0f;   // 1/TEMP, TEMP=0.5

constexpr int NEG_V = B_ * N_ * M_ * K_;    // 1536 neg vectors
constexpr int POS_V = B_ * K_;              // 24 pos vectors
constexpr int SEG   = 4;                    // D split into 4 segments
constexpr int SEG_F4 = D_ / 4 / SEG;        // 2048 float4 per segment
constexpr int NEG_BLOCKS = NEG_V * SEG;     // 6144
constexpr int POS_BLOCKS = POS_V * SEG;     // 96
constexpr int TOT_BLOCKS = NEG_BLOCKS + POS_BLOCKS;  // 6240

// ws poisoned to 0xAA bytes before every timed launch:
//  - as uint32 counter: starts at 0xAAAAAAAA (deterministic)
//  - as float accumulator: 0xAAAAAAAA == -3.03e-13 (numerically zero)
constexpr unsigned int POISON_U32 = 0xAAAAAAAAu;

#define FMA4(acc, p, q) \
  acc += (p).x * (q).x + (p).y * (q).y + (p).z * (q).z + (p).w * (q).w

// ---------------------------------------------------------------------------
// One block = one (vector, D-segment) partial. 6240 blocks -> ~97 waves/CU
// lifetime (R4 had only 24, latency-bound at 184us). Each thread issues 16
// back-to-back float4 loads via fully-unrolled register arrays (forces the
// MLP the compiler refused at VGPR=32). Partials accumulate via float
// atomicAdd onto the poisoned-as-zero ws; the last block (acq_rel counter)
// computes cosines from the sums + masked logsumexp + final scalar.
// ---------------------------------------------------------------------------
__global__ __launch_bounds__(256) void logits_kernel(
    const float* __restrict__ fmaps, const float* __restrict__ fmaps_pos,
    const float* __restrict__ fmaps_neg,
    const int* __restrict__ gt_labels, const int* __restrict__ gt_label_negs,
    float* __restrict__ neg_dot, float* __restrict__ neg_nv,
    float* __restrict__ pos_dot, float* __restrict__ pos_nx,
    float* __restrict__ pos_np,
    unsigned int* __restrict__ done_cnt, float* __restrict__ out) {
  __shared__ float s[3][4];
  __shared__ bool s_last;
  const int t = threadIdx.x;
  const int wid = t >> 6, lane = t & 63;

  if (blockIdx.x < NEG_BLOCKS) {
    // ---- neg partial: vid = ((b*N + n)*M + m)*K + k ----
    const int vid = blockIdx.x / SEG;
    const int seg = blockIdx.x % SEG;
    const int k = vid % K_;
    const int b = vid / (N_ * M_ * K_);
    const size_t xbase = (((size_t)b * J_ + (J_ - 1)) * K_ + k) * (size_t)D_;
    const float4* __restrict__ xs =
        (const float4*)(fmaps + xbase) + (size_t)seg * SEG_F4;
    const float4* __restrict__ vs =
        (const float4*)(fmaps_neg + (size_t)vid * D_) + (size_t)seg * SEG_F4;

    float4 a[8], c[8];
#pragma unroll
    for (int u = 0; u < 8; ++u) a[u] = xs[t + 256 * u];
#pragma unroll
    for (int u = 0; u < 8; ++u) c[u] = vs[t + 256 * u];

    float dot = 0.f, nv = 0.f;
#pragma unroll
    for (int u = 0; u < 8; ++u) { FMA4(dot, a[u], c[u]); FMA4(nv, c[u], c[u]); }

    for (int off = 32; off > 0; off >>= 1) {
      dot += __shfl_down(dot, off, 64);
      nv  += __shfl_down(nv,  off, 64);
    }
    if (lane == 0) { s[0][wid] = dot; s[1][wid] = nv; }
    __syncthreads();
    if (t == 0) {
      dot = s[0][0] + s[0][1] + s[0][2] + s[0][3];
      nv  = s[1][0] + s[1][1] + s[1][2] + s[1][3];
      atomicAdd(neg_dot + vid, dot);
      atomicAdd(neg_nv  + vid, nv);
    }
  } else {
    // ---- pos partial: vid = b*K + k ----
    const int pid = blockIdx.x - NEG_BLOCKS;
    const int vid = pid / SEG;
    const int seg = pid % SEG;
    const int b = vid / K_, k = vid % K_;
    const size_t base = (((size_t)b * J_ + (J_ - 1)) * K_ + k) * (size_t)D_;
    const float4* __restrict__ xs =
        (const float4*)(fmaps + base) + (size_t)seg * SEG_F4;
    const float4* __restrict__ ps =
        (const float4*)(fmaps_pos + base) + (size_t)seg * SEG_F4;

    float4 a[8], c[8];
#pragma unroll
    for (int u = 0; u < 8; ++u) a[u] = xs[t + 256 * u];
#pragma unroll
    for (int u = 0; u < 8; ++u) c[u] = ps[t + 256 * u];

    float dot = 0.f, nx = 0.f, np = 0.f;
#pragma unroll
    for (int u = 0; u < 8; ++u) {
      FMA4(dot, a[u], c[u]); FMA4(nx, a[u], a[u]); FMA4(np, c[u], c[u]);
    }

    for (int off = 32; off > 0; off >>= 1) {
      dot += __shfl_down(dot, off, 64);
      nx  += __shfl_down(nx,  off, 64);
      np  += __shfl_down(np,  off, 64);
    }
    if (lane == 0) { s[0][wid] = dot; s[1][wid] = nx; s[2][wid] = np; }
    __syncthreads();
    if (t == 0) {
      dot = s[0][0] + s[0][1] + s[0][2] + s[0][3];
      nx  = s[1][0] + s[1][1] + s[1][2] + s[1][3];
      np  = s[2][0] + s[2][1] + s[2][2] + s[2][3];
      atomicAdd(pos_dot + vid, dot);
      atomicAdd(pos_nx  + vid, nx);
      atomicAdd(pos_np  + vid, np);
    }
  }

  // ---- completion count: last block to finish does the logsumexp ----
  __syncthreads();
  if (t == 0) {
    unsigned int prev = __hip_atomic_fetch_add(done_cnt, 1u, __ATOMIC_ACQ_REL,
                                               __HIP_MEMORY_SCOPE_AGENT);
    s_last = (prev == POISON_U32 + (unsigned int)TOT_BLOCKS - 1u);
  }
  __syncthreads();
  if (!s_last) return;

  // ---- masked logsumexp. 8 threads per (b,k); logits are bounded in
  // [-2,2] (cosine/TEMP) so no max-subtraction is needed. ----
  const int bk = t >> 3;   // 0..31 (24 used)
  const int sub = t & 7;   // 0..7, each covers 8 of the 64 negs
  float partial = 0.f;
  if (bk < POS_V) {
    const int b = bk / K_, k = bk % K_;
    const int lbl = gt_labels[b * J_ + (J_ - 1)];
    const float nxs = sqrtf(pos_nx[bk]);
    for (int u = 0; u < 8; ++u) {
      const int i = sub * 8 + u;                     // 0..63 (n*M+m)
      if (gt_label_negs[b * (N_ * M_) + i] == lbl) {
        const int nidx = (b * (N_ * M_) + i) * K_ + k;
        const float neg = neg_dot[nidx] /
            fmaxf(nxs * sqrtf(neg_nv[nidx]), EPS_) * TEMP_INV;
        partial += expf(neg);
      }
    }
  }
  // reduce the 8-lane subgroup (lanes contiguous within a wave)
  for (int off = 1; off < 8; off <<= 1) partial += __shfl_xor(partial, off, 64);

  float contrib = 0.f;
  if (bk < POS_V && sub == 0) {
    const float p = pos_dot[bk] /
        fmaxf(sqrtf(pos_nx[bk]) * sqrtf(pos_np[bk]), EPS_) * TEMP_INV;
    contrib = logf(partial + expf(p)) - p;
  }
  // sum contribs across the block (nonzero lanes are sparse; zeros are inert)
  for (int off = 32; off > 0; off >>= 1) contrib += __shfl_down(contrib, off, 64);
  if (lane == 0) s[0][wid] = contrib;
  __syncthreads();
  if (t == 0) {
    out[0] = (s[0][0] + s[0][1] + s[0][2] + s[0][3]) / (2.0f * (float)B_);
  }
}

// ---------------------------------------------------------------------------
extern "C" void kernel_launch(void* const* d_in, const int* in_sizes, int n_in,
                              void* d_out, int out_size, void* d_ws, size_t ws_size,
                              hipStream_t stream) {
  const float* fmaps         = (const float*)d_in[0];
  const float* fmaps_pos     = (const float*)d_in[1];
  const float* fmaps_neg     = (const float*)d_in[2];
  const int*   gt_labels     = (const int*)d_in[3];
  const int*   gt_label_negs = (const int*)d_in[4];
  float* out = (float*)d_out;

  // ws layout (floats):
  // [0,1536) neg_dot | [1536,3072) neg_nv | [3072,3096) pos_dot
  // [3096,3120) pos_nx | [3120,3144) pos_np | [3144] counter
  float* ws      = (float*)d_ws;
  float* neg_dot = ws;
  float* neg_nv  = ws + NEG_V;
  float* pos_dot = ws + 2 * NEG_V;
  float* pos_nx  = ws + 2 * NEG_V + POS_V;
  float* pos_np  = ws + 2 * NEG_V + 2 * POS_V;
  unsigned int* done_cnt = (unsigned int*)(ws + 2 * NEG_V + 3 * POS_V);

  logits_kernel<<<TOT_BLOCKS, 256, 0, stream>>>(
      fmaps, fmaps_pos, fmaps_neg, gt_labels, gt_label_negs,
      neg_dot, neg_nv, pos_dot, pos_nx, pos_np, done_cnt, out);
}

// Round 6
// 288.366 us; speedup vs baseline: 2.0785x; 2.0785x over previous
//
#include <hip/hip_runtime.h>
#include <math.h>

// Problem constants (from setup_inputs): B=8, J=4, N=4, M=16, K=3, D=32768
constexpr int B_ = 8;
constexpr int J_ = 4;
constexpr int N_ = 4;
constexpr int M_ = 16;
constexpr int K_ = 3;
constexpr int D_ = 32768;
constexpr float EPS_ = 1e-8f;
constexpr float TEMP_INV = 2.0f;   // 1/TEMP, TEMP=0.5

constexpr int NEG_V = B_ * N_ * M_ * K_;    // 1536 neg vectors
constexpr int POS_V = B_ * K_;              // 24 pos vectors
constexpr int SEG   = 4;                    // D split into 4 segments
constexpr int SEG_F4 = D_ / 4 / SEG;        // 2048 float4 per segment
constexpr int NEG_BLOCKS = NEG_V * SEG;     // 6144
constexpr int POS_BLOCKS = POS_V * SEG;     // 96
constexpr int TOT_BLOCKS = NEG_BLOCKS + POS_BLOCKS;  // 6240

#define FMA4(acc, p, q) \
  acc += (p).x * (q).x + (p).y * (q).y + (p).z * (q).z + (p).w * (q).w

// ---------------------------------------------------------------------------
// Kernel A: one block = one (vector, D-segment) partial. ATOMIC-FREE:
// R4/R5 post-mortem showed the agent-scope same-address RMW chain costs
// ~45 ns per block (1560 RMWs = +67us, 6240 RMWs+floats = +280us) — it was
// the entire regression. Partials go to UNIQUE ws slots via plain stores.
// Neg blocks need only dot & |v|^2; |x|^2 comes from the pos blocks (which
// read x anyway), avoiding 64x redundant norm work.
// ---------------------------------------------------------------------------
__global__ __launch_bounds__(256) void partial_kernel(
    const float* __restrict__ fmaps, const float* __restrict__ fmaps_pos,
    const float* __restrict__ fmaps_neg,
    float* __restrict__ neg_dot_p, float* __restrict__ neg_nv_p,
    float* __restrict__ pos_dot_p, float* __restrict__ pos_nx_p,
    float* __restrict__ pos_np_p) {
  __shared__ float s[3][4];
  const int t = threadIdx.x;
  const int wid = t >> 6, lane = t & 63;

  if (blockIdx.x < NEG_BLOCKS) {
    // ---- neg partial: vid = ((b*N + n)*M + m)*K + k ----
    const int vid = blockIdx.x / SEG;
    const int seg = blockIdx.x % SEG;
    const int k = vid % K_;
    const int b = vid / (N_ * M_ * K_);
    const size_t xbase = (((size_t)b * J_ + (J_ - 1)) * K_ + k) * (size_t)D_;
    const float4* __restrict__ xs =
        (const float4*)(fmaps + xbase) + (size_t)seg * SEG_F4;
    const float4* __restrict__ vs =
        (const float4*)(fmaps_neg + (size_t)vid * D_) + (size_t)seg * SEG_F4;

    float dot = 0.f, nv = 0.f;
#pragma unroll
    for (int u = 0; u < SEG_F4 / 256; ++u) {   // 8 fully-unrolled iters
      float4 a = xs[t + 256 * u];
      float4 c = vs[t + 256 * u];
      FMA4(dot, a, c);
      FMA4(nv, c, c);
    }
    for (int off = 32; off > 0; off >>= 1) {
      dot += __shfl_down(dot, off, 64);
      nv  += __shfl_down(nv,  off, 64);
    }
    if (lane == 0) { s[0][wid] = dot; s[1][wid] = nv; }
    __syncthreads();
    if (t == 0) {
      neg_dot_p[blockIdx.x] = s[0][0] + s[0][1] + s[0][2] + s[0][3];
      neg_nv_p[blockIdx.x]  = s[1][0] + s[1][1] + s[1][2] + s[1][3];
    }
  } else {
    // ---- pos partial: vid = b*K + k ----
    const int pid = blockIdx.x - NEG_BLOCKS;
    const int vid = pid / SEG;
    const int seg = pid % SEG;
    const int b = vid / K_, k = vid % K_;
    const size_t base = (((size_t)b * J_ + (J_ - 1)) * K_ + k) * (size_t)D_;
    const float4* __restrict__ xs =
        (const float4*)(fmaps + base) + (size_t)seg * SEG_F4;
    const float4* __restrict__ ps =
        (const float4*)(fmaps_pos + base) + (size_t)seg * SEG_F4;

    float dot = 0.f, nx = 0.f, np = 0.f;
#pragma unroll
    for (int u = 0; u < SEG_F4 / 256; ++u) {
      float4 a = xs[t + 256 * u];
      float4 c = ps[t + 256 * u];
      FMA4(dot, a, c);
      FMA4(nx, a, a);
      FMA4(np, c, c);
    }
    for (int off = 32; off > 0; off >>= 1) {
      dot += __shfl_down(dot, off, 64);
      nx  += __shfl_down(nx,  off, 64);
      np  += __shfl_down(np,  off, 64);
    }
    if (lane == 0) { s[0][wid] = dot; s[1][wid] = nx; s[2][wid] = np; }
    __syncthreads();
    if (t == 0) {
      pos_dot_p[pid] = s[0][0] + s[0][1] + s[0][2] + s[0][3];
      pos_nx_p[pid]  = s[1][0] + s[1][1] + s[1][2] + s[1][3];
      pos_np_p[pid]  = s[2][0] + s[2][1] + s[2][2] + s[2][3];
    }
  }
}

// ---------------------------------------------------------------------------
// Kernel B: single block. Sum the 4 partials per vector, form cosines in
// LDS, masked logsumexp, final scalar. ~12K ws loads -> a few us.
// ---------------------------------------------------------------------------
__global__ __launch_bounds__(256) void finish_kernel(
    const float* __restrict__ neg_dot_p, const float* __restrict__ neg_nv_p,
    const float* __restrict__ pos_dot_p, const float* __restrict__ pos_nx_p,
    const float* __restrict__ pos_np_p,
    const int* __restrict__ gt_labels, const int* __restrict__ gt_label_negs,
    float* __restrict__ out) {
  __shared__ float l_neg[NEG_V];
  __shared__ float l_pos[POS_V];
  __shared__ float l_nxs[POS_V];
  __shared__ float red[4];
  const int t = threadIdx.x;

  // pos logits + |x| per (b,k)
  if (t < POS_V) {
    float dot = 0.f, nx = 0.f, np = 0.f;
    for (int s2 = 0; s2 < SEG; ++s2) {
      dot += pos_dot_p[t * SEG + s2];
      nx  += pos_nx_p[t * SEG + s2];
      np  += pos_np_p[t * SEG + s2];
    }
    const float nxs = sqrtf(nx);
    l_nxs[t] = nxs;
    l_pos[t] = dot / fmaxf(nxs * sqrtf(np), EPS_) * TEMP_INV;
  }
  __syncthreads();

  // neg logits (6 vids per thread)
  for (int vid = t; vid < NEG_V; vid += 256) {
    float dot = 0.f, nv = 0.f;
    for (int s2 = 0; s2 < SEG; ++s2) {
      dot += neg_dot_p[vid * SEG + s2];
      nv  += neg_nv_p[vid * SEG + s2];
    }
    const int k = vid % K_;
    const int b = vid / (N_ * M_ * K_);
    l_neg[vid] =
        dot / fmaxf(l_nxs[b * K_ + k] * sqrtf(nv), EPS_) * TEMP_INV;
  }
  __syncthreads();

  // masked logsumexp: 8 threads per (b,k). Logits bounded in [-2,2]
  // (cosine/TEMP) so no max-shift needed.
  const int bk = t >> 3, sub = t & 7;
  float partial = 0.f;
  if (bk < POS_V) {
    const int b = bk / K_, k = bk % K_;
    const int lbl = gt_labels[b * J_ + (J_ - 1)];
    for (int u = 0; u < 8; ++u) {
      const int i = sub * 8 + u;                  // n*M+m in 0..63
      if (gt_label_negs[b * (N_ * M_) + i] == lbl) {
        partial += expf(l_neg[(b * (N_ * M_) + i) * K_ + k]);
      }
    }
  }
  for (int off = 1; off < 8; off <<= 1) partial += __shfl_xor(partial, off, 64);

  float contrib = 0.f;
  if (bk < POS_V && sub == 0) {
    const float p = l_pos[bk];
    contrib = logf(partial + expf(p)) - p;
  }
  for (int off = 32; off > 0; off >>= 1) contrib += __shfl_down(contrib, off, 64);
  const int wid = t >> 6, lane = t & 63;
  if (lane == 0) red[wid] = contrib;
  __syncthreads();
  if (t == 0) out[0] = (red[0] + red[1] + red[2] + red[3]) / (2.0f * (float)B_);
}

// ---------------------------------------------------------------------------
extern "C" void kernel_launch(void* const* d_in, const int* in_sizes, int n_in,
                              void* d_out, int out_size, void* d_ws, size_t ws_size,
                              hipStream_t stream) {
  const float* fmaps         = (const float*)d_in[0];
  const float* fmaps_pos     = (const float*)d_in[1];
  const float* fmaps_neg     = (const float*)d_in[2];
  const int*   gt_labels     = (const int*)d_in[3];
  const int*   gt_label_negs = (const int*)d_in[4];
  float* out = (float*)d_out;

  // ws layout (floats), all plain stores, no init needed:
  // [0,6144)      neg_dot_p
  // [6144,12288)  neg_nv_p
  // [12288,12384) pos_dot_p
  // [12384,12480) pos_nx_p
  // [12480,12576) pos_np_p
  float* ws        = (float*)d_ws;
  float* neg_dot_p = ws;
  float* neg_nv_p  = ws + NEG_BLOCKS;
  float* pos_dot_p = ws + 2 * NEG_BLOCKS;
  float* pos_nx_p  = ws + 2 * NEG_BLOCKS + POS_BLOCKS;
  float* pos_np_p  = ws + 2 * NEG_BLOCKS + 2 * POS_BLOCKS;

  partial_kernel<<<TOT_BLOCKS, 256, 0, stream>>>(
      fmaps, fmaps_pos, fmaps_neg,
      neg_dot_p, neg_nv_p, pos_dot_p, pos_nx_p, pos_np_p);
  finish_kernel<<<1, 256, 0, stream>>>(
      neg_dot_p, neg_nv_p, pos_dot_p, pos_nx_p, pos_np_p,
      gt_labels, gt_label_negs, out);
}